// Round 2
// baseline (435.290 us; speedup 1.0000x reference)
//
#include <hip/hip_runtime.h>
#include <stdint.h>

// Problem constants
#define Bn 8
#define Tn 2048
#define Cn 1024
#define Mn (Bn * Tn)
#define NTRI 136   // causal 128x128 tiles per batch: 16*17/2
#define NLIN2 72   // k2 tiles per batch: BM=128,BN=256 -> sum ceil((qt+1)/2)

typedef __attribute__((ext_vector_type(4))) float f32x4;
typedef _Float16 f16;
typedef __attribute__((ext_vector_type(8))) _Float16 f16x8;
typedef uint16_t u16;
typedef uint32_t u32;

static __device__ __forceinline__ u16 f2h(float f) {
  union { f16 h; u16 u; } c; c.h = (f16)f; return c.u;
}
static __device__ __forceinline__ f32x4 mfmaH(f16x8 a, f16x8 b, f32x4 c) {
  return __builtin_amdgcn_mfma_f32_16x16x32_f16(a, b, c, 0, 0, 0);
}
// async global->LDS, 16B/lane; LDS dest = wave-uniform base + lane*16.
static __device__ __forceinline__ void gld16(const void* g, void* l) {
  __builtin_amdgcn_global_load_lds(
      (const __attribute__((address_space(1))) u32*)g,
      (__attribute__((address_space(3))) u32*)l, 16, 0, 0);
}

// ---------------------------------------------------------------------------
// ksplitW: W fp32 -> fp16 hi only.
// ---------------------------------------------------------------------------
__global__ __launch_bounds__(256) void ksplitW(const float* __restrict__ s,
                                               u16* __restrict__ hi) {
  size_t i = ((size_t)blockIdx.x * 256 + threadIdx.x) * 8;
  float4 a = *(const float4*)(s + i), b = *(const float4*)(s + i + 4);
  float f[8] = {a.x, a.y, a.z, a.w, b.x, b.y, b.z, b.w};
  union { u16 u[8]; uint4 v; } H;
#pragma unroll
  for (int j = 0; j < 8; ++j) H.u[j] = f2h(f[j]);
  *(uint4*)(hi + i) = H.v;
}

// ---------------------------------------------------------------------------
// ksplitX: x fp32 -> fp16 hi + fp16 lo residual (~22-bit effective).
// ---------------------------------------------------------------------------
__global__ __launch_bounds__(256) void ksplitX(const float* __restrict__ s,
                                               u16* __restrict__ hi,
                                               u16* __restrict__ lo) {
  size_t i = ((size_t)blockIdx.x * 256 + threadIdx.x) * 8;
  float4 a = *(const float4*)(s + i), b = *(const float4*)(s + i + 4);
  float f[8] = {a.x, a.y, a.z, a.w, b.x, b.y, b.z, b.w};
  union { u16 u[8]; uint4 v; } H, L;
#pragma unroll
  for (int j = 0; j < 8; ++j) {
    f16 h = (f16)f[j];
    union { f16 h; u16 u; } ch; ch.h = h;
    H.u[j] = ch.u;
    L.u[j] = f2h(f[j] - (float)h);
  }
  *(uint4*)(hi + i) = H.v;
  *(uint4*)(lo + i) = L.v;
}

// ---------------------------------------------------------------------------
// K1: xh = x_h @ W_h^T  (1 fp16 MFMA term). 128x128 tile, BK=64 as two
// [128][32] half-buffers (bank-identical to the proven BK=32 layout).
// ---------------------------------------------------------------------------
__global__ __launch_bounds__(256) void k1_xh(const u16* __restrict__ x_h,
                                             const u16* __restrict__ W_h,
                                             u16* __restrict__ xh) {
  __shared__ __align__(16) u16 Ah[8192], Bh[8192];
  const int tid = threadIdx.x;
  const int m0 = blockIdx.x * 128, n0 = blockIdx.y * 128;
  const int wave = tid >> 6, lane = tid & 63;
  const int wrow = (wave >> 1) * 64, wcol = (wave & 1) * 64;
  const int quad = lane >> 4, l16 = lane & 15;

  f32x4 acc[4][4] = {};

  for (int k0 = 0; k0 < Cn; k0 += 64) {
#pragma unroll
    for (int i = 0; i < 4; ++i) {
      int chunk = i * 256 + tid;
      int kk = chunk >> 9, row = (chunk >> 2) & 127, c8 = (chunk & 3) * 8;
      gld16(x_h + (size_t)(m0 + row) * Cn + k0 + kk * 32 + c8, Ah + chunk * 8);
      gld16(W_h + (size_t)(n0 + row) * Cn + k0 + kk * 32 + c8, Bh + chunk * 8);
    }
    __syncthreads();
#pragma unroll
    for (int kk = 0; kk < 2; ++kk) {
      f16x8 a[4], b[4];
#pragma unroll
      for (int i = 0; i < 4; ++i) {
        a[i] = *(const f16x8*)(Ah + kk * 4096 + (wrow + i * 16 + l16) * 32 + quad * 8);
        b[i] = *(const f16x8*)(Bh + kk * 4096 + (wcol + i * 16 + l16) * 32 + quad * 8);
      }
#pragma unroll
      for (int mi = 0; mi < 4; ++mi)
#pragma unroll
        for (int ni = 0; ni < 4; ++ni)
          acc[mi][ni] = mfmaH(a[mi], b[ni], acc[mi][ni]);
    }
    __syncthreads();
  }
#pragma unroll
  for (int mi = 0; mi < 4; ++mi)
#pragma unroll
    for (int ni = 0; ni < 4; ++ni)
#pragma unroll
      for (int r = 0; r < 4; ++r) {
        int row = wrow + mi * 16 + quad * 4 + r;
        int col = wcol + ni * 16 + l16;
        xh[(size_t)(m0 + row) * Cn + n0 + col] = f2h(acc[mi][ni][r]);
      }
}

// ---------------------------------------------------------------------------
// K2: S = (x_h + x_l) @ xh^T (2 terms); causal BM=128 x BN=256 tiles.
// Memory-hierarchy-BW bound -> widen BN (B has 1 plane, A has 2):
// bytes/output 48 -> 32. 512 thr / 8 waves (2x4, 64x64 each), BK=32,
// LDS 32KB -> 4 blocks/CU (32 waves/CU for MLP). P/mt/lt keep the
// 128-granular packed layout so k3/k4 are unchanged; each wave's 64 cols
// lie in one 128-half: st128 = 2*bcol + (wc>>1), guarded st128 <= qt.
// ---------------------------------------------------------------------------
__global__ __launch_bounds__(512) void k2_scores(const u16* __restrict__ x_h,
                                                 const u16* __restrict__ x_l,
                                                 const u16* __restrict__ xh,
                                                 u16* __restrict__ P,
                                                 float* __restrict__ mt,
                                                 float* __restrict__ lt) {
  __shared__ __align__(16) union {
    struct { u16 Ah[4096], Al[4096], Bh[8192]; } s;  // [128][32],[128][32],[256][32]
    struct { float Mrow[4][128]; float Lrow[4][128]; } e;
  } u;
  const int tid = threadIdx.x;
  const int bL = blockIdx.y;
  const int lin = blockIdx.x;
  int qt = 0, cum = 0;
  while (cum + ((qt >> 1) + 1) <= lin) { cum += (qt >> 1) + 1; qt++; }
  const int bcol = lin - cum;
  const int t0 = qt * 128, s0 = bcol * 256;
  const int wave = tid >> 6, lane = tid & 63;
  const int wc = wave & 3;
  const int wrow = (wave >> 2) * 64, wcol = wc * 64;
  const int quad = lane >> 4, l16 = lane & 15;

  f32x4 acc[4][4] = {};
  const size_t abase = ((size_t)bL * Tn + t0) * Cn;
  const size_t bbase = ((size_t)bL * Tn + s0) * Cn;
  const int arow = tid >> 2, ac8 = (tid & 3) * 8;

  for (int k0 = 0; k0 < Cn; k0 += 32) {
    size_t aoff = abase + (size_t)arow * Cn + k0 + ac8;
    gld16(x_h + aoff, u.s.Ah + tid * 8);
    gld16(x_l + aoff, u.s.Al + tid * 8);
#pragma unroll
    for (int i = 0; i < 2; ++i) {
      int ch = i * 512 + tid;
      int row = ch >> 2, c8 = (ch & 3) * 8;
      gld16(xh + bbase + (size_t)row * Cn + k0 + c8, u.s.Bh + ch * 8);
    }
    __syncthreads();
    f16x8 b[4];
#pragma unroll
    for (int ni = 0; ni < 4; ++ni)
      b[ni] = *(const f16x8*)(u.s.Bh + (wcol + ni * 16 + l16) * 32 + quad * 8);
#pragma unroll
    for (int mi = 0; mi < 4; ++mi) {
      f16x8 ah = *(const f16x8*)(u.s.Ah + (wrow + mi * 16 + l16) * 32 + quad * 8);
      f16x8 al = *(const f16x8*)(u.s.Al + (wrow + mi * 16 + l16) * 32 + quad * 8);
#pragma unroll
      for (int ni = 0; ni < 4; ++ni) {
        acc[mi][ni] = mfmaH(ah, b[ni], acc[mi][ni]);
        acc[mi][ni] = mfmaH(al, b[ni], acc[mi][ni]);
      }
    }
    __syncthreads();
  }

  // ---- epilogue: mask, per-row max (per 128-half), exp, stats, packed-P ----
  float rm[4][4];
#pragma unroll
  for (int mi = 0; mi < 4; ++mi)
#pragma unroll
    for (int r = 0; r < 4; ++r) {
      int row = wrow + mi * 16 + quad * 4 + r;
      float m = -1e30f;
#pragma unroll
      for (int ni = 0; ni < 4; ++ni) {
        int scol = s0 + wcol + ni * 16 + l16;
        if (scol >= t0 + row) acc[mi][ni][r] = -1e30f;
        m = fmaxf(m, acc[mi][ni][r]);
      }
      m = fmaxf(m, __shfl_xor(m, 1));
      m = fmaxf(m, __shfl_xor(m, 2));
      m = fmaxf(m, __shfl_xor(m, 4));
      m = fmaxf(m, __shfl_xor(m, 8));
      rm[mi][r] = m;
    }
  if (l16 == 0) {
#pragma unroll
    for (int mi = 0; mi < 4; ++mi)
#pragma unroll
      for (int r = 0; r < 4; ++r)
        u.e.Mrow[wc][wrow + mi * 16 + quad * 4 + r] = rm[mi][r];
  }
  __syncthreads();
  const int h2 = (wc >> 1) * 2;  // partner pair covering this 128-half
  float rs[4][4];
#pragma unroll
  for (int mi = 0; mi < 4; ++mi)
#pragma unroll
    for (int r = 0; r < 4; ++r) {
      int row = wrow + mi * 16 + quad * 4 + r;
      float m2 = fmaxf(u.e.Mrow[h2][row], u.e.Mrow[h2 + 1][row]);
      float s = 0.f;
#pragma unroll
      for (int ni = 0; ni < 4; ++ni) {
        int scol = s0 + wcol + ni * 16 + l16;
        float p = (scol < t0 + row) ? __expf(acc[mi][ni][r] - m2) : 0.0f;
        acc[mi][ni][r] = p;
        s += p;
      }
      s += __shfl_xor(s, 1);
      s += __shfl_xor(s, 2);
      s += __shfl_xor(s, 4);
      s += __shfl_xor(s, 8);
      rs[mi][r] = s;
      rm[mi][r] = m2;
    }
  if (l16 == 0) {
#pragma unroll
    for (int mi = 0; mi < 4; ++mi)
#pragma unroll
      for (int r = 0; r < 4; ++r)
        u.e.Lrow[wc][wrow + mi * 16 + quad * 4 + r] = rs[mi][r];
  }
  __syncthreads();
  const int st128 = bcol * 2 + (wc >> 1);
  if (st128 <= qt) {  // even-qt diagonal rows have a dead right half-tile
    if ((wc & 1) == 0 && l16 == 0) {
#pragma unroll
      for (int mi = 0; mi < 4; ++mi)
#pragma unroll
        for (int r = 0; r < 4; ++r) {
          int row = wrow + mi * 16 + quad * 4 + r;
          size_t rI = (size_t)bL * Tn + t0 + row;
          mt[rI * 16 + st128] = rm[mi][r];
          lt[rI * 16 + st128] = u.e.Lrow[wc][row] + u.e.Lrow[wc + 1][row];
        }
    }
    const size_t pbase = (size_t)(bL * NTRI + qt * (qt + 1) / 2 + st128) * 16384;
#pragma unroll
    for (int mi = 0; mi < 4; ++mi)
#pragma unroll
      for (int ni = 0; ni < 4; ++ni)
#pragma unroll
        for (int r = 0; r < 4; ++r) {
          int row = wrow + mi * 16 + quad * 4 + r;
          int pcol = (wcol & 64) + ni * 16 + l16;
          P[pbase + row * 128 + pcol] = f2h(acc[mi][ni][r]);
        }
  }
}

// ---------------------------------------------------------------------------
// K3: per-row global max M and inverse denom Li. Row t=0 -> Li=0.
// ---------------------------------------------------------------------------
__global__ __launch_bounds__(256) void k3_stats(const float* __restrict__ mt,
                                                const float* __restrict__ lt,
                                                float* __restrict__ Mr,
                                                float* __restrict__ Li) {
  int r = blockIdx.x * 256 + threadIdx.x;
  int t = r & (Tn - 1);
  int nt = (t == 0) ? 0 : (((t - 1) >> 7) + 1);
  float M = -1e30f;
  for (int i = 0; i < nt; ++i) M = fmaxf(M, mt[(size_t)r * 16 + i]);
  float L = 0.f;
  for (int i = 0; i < nt; ++i) L += lt[(size_t)r * 16 + i] * __expf(mt[(size_t)r * 16 + i] - M);
  Mr[r] = M;
  Li[r] = (L > 0.f) ? 1.f / L : 0.f;
}

// ---------------------------------------------------------------------------
// ktr: xhT[b][c][s] = xh[b][s][c]  (fp16, 128x128 LDS tiles)
// ---------------------------------------------------------------------------
__global__ __launch_bounds__(256) void ktr(const u16* __restrict__ src,
                                           u16* __restrict__ dst) {
  __shared__ __align__(16) u16 S[128 * 136];
  const int t0 = blockIdx.x * 128, c0 = blockIdx.y * 128, b = blockIdx.z;
  const int tid = threadIdx.x;
#pragma unroll
  for (int i = 0; i < 8; ++i) {
    int chunk = tid + i * 256;
    int row = chunk >> 4, c8 = (chunk & 15) * 8;
    uint4 v = *(const uint4*)(src + ((size_t)b * Tn + t0 + row) * Cn + c0 + c8);
    *(uint4*)(S + row * 136 + c8) = v;
  }
  __syncthreads();
#pragma unroll
  for (int i = 0; i < 8; ++i) {
    int chunk = tid + i * 256;
    int crow = chunk >> 4, t8 = (chunk & 15) * 8;
    union { u16 s[8]; uint4 v; } o;
#pragma unroll
    for (int j = 0; j < 8; ++j) o.s[j] = S[(t8 + j) * 136 + crow];
    *(uint4*)(dst + ((size_t)b * Cn + c0 + crow) * Tn + t0 + t8) = o.v;
  }
}

// ---------------------------------------------------------------------------
// K4: out = -( (P*alpha) @ xh ), alpha folded into the A fragment.
// A = packed P tiles; B = xhT (k=s contig). BK=64 (two [128][32] halves).
// ---------------------------------------------------------------------------
__global__ __launch_bounds__(256) void k4_out(const u16* __restrict__ P,
                                              const u16* __restrict__ xhT,
                                              const float* __restrict__ mt,
                                              const float* __restrict__ Mr,
                                              const float* __restrict__ Li,
                                              float* __restrict__ out) {
  __shared__ __align__(16) u16 Ap[8192], Bp[8192];
  const int tid = threadIdx.x;
  const int tt = 15 - blockIdx.x;  // heavy tiles first
  const int cn = blockIdx.y, bL = blockIdx.z;
  const int t0 = tt * 128, c0 = cn * 128;
  const int wave = tid >> 6, lane = tid & 63;
  const int wrow = (wave >> 1) * 64, wcol = (wave & 1) * 64;
  const int quad = lane >> 4, l16 = lane & 15;

  f32x4 acc[4][4] = {};
  size_t rI[4]; float MrL[4], LiL[4];
#pragma unroll
  for (int mi = 0; mi < 4; ++mi) {
    rI[mi] = (size_t)bL * Tn + t0 + wrow + mi * 16 + l16;
    MrL[mi] = Mr[rI[mi]];
    LiL[mi] = Li[rI[mi]];
  }
  const size_t bbase = ((size_t)bL * Cn + c0) * Tn;

  for (int st = 0; st <= tt; ++st) {
    f16 ah[4];
#pragma unroll
    for (int mi = 0; mi < 4; ++mi)
      ah[mi] = (f16)(__expf(mt[rI[mi] * 16 + st] - MrL[mi]) * LiL[mi]);
    const size_t pbase = (size_t)(bL * NTRI + tt * (tt + 1) / 2 + st) * 16384;
#pragma unroll 1
    for (int kl = 0; kl < 128; kl += 64) {
#pragma unroll
      for (int i = 0; i < 4; ++i) {
        int chunk = i * 256 + tid;
        int kk = chunk >> 9, row = (chunk >> 2) & 127, c8 = (chunk & 3) * 8;
        gld16(P + pbase + (size_t)row * 128 + kl + kk * 32 + c8, Ap + chunk * 8);
        gld16(xhT + bbase + (size_t)row * Tn + st * 128 + kl + kk * 32 + c8, Bp + chunk * 8);
      }
      __syncthreads();
#pragma unroll
      for (int kk = 0; kk < 2; ++kk) {
        f16x8 a[4], b[4];
#pragma unroll
        for (int i = 0; i < 4; ++i) {
          a[i] = *(const f16x8*)(Ap + kk * 4096 + (wrow + i * 16 + l16) * 32 + quad * 8);
          f16x8 sv;
#pragma unroll
          for (int j = 0; j < 8; ++j) sv[j] = ah[i];
          a[i] = a[i] * sv;
          b[i] = *(const f16x8*)(Bp + kk * 4096 + (wcol + i * 16 + l16) * 32 + quad * 8);
        }
#pragma unroll
        for (int mi = 0; mi < 4; ++mi)
#pragma unroll
          for (int ni = 0; ni < 4; ++ni)
            acc[mi][ni] = mfmaH(a[mi], b[ni], acc[mi][ni]);
      }
      __syncthreads();
    }
  }
#pragma unroll
  for (int mi = 0; mi < 4; ++mi)
#pragma unroll
    for (int ni = 0; ni < 4; ++ni)
#pragma unroll
      for (int r = 0; r < 4; ++r) {
        int row = wrow + mi * 16 + quad * 4 + r;
        int col = wcol + ni * 16 + l16;
        out[((size_t)bL * Tn + t0 + row) * Cn + c0 + col] = -acc[mi][ni][r];
      }
}

// ---------------------------------------------------------------------------
extern "C" void kernel_launch(void* const* d_in, const int* in_sizes, int n_in,
                              void* d_out, int out_size, void* d_ws, size_t ws_size,
                              hipStream_t stream) {
  (void)in_sizes; (void)n_in; (void)out_size;
  const float* x = (const float*)d_in[0];
  const float* W = (const float*)d_in[1];
  float* out = (float*)d_out;

  // full-batch path needs ~140.6 MB; else fall back to 2 chunks (~71 MB)
  const size_t FULL_NEED = 3ull * Mn * Cn * 2 + (size_t)Bn * NTRI * 16384 * 2 +
                           (size_t)Cn * Cn * 2 + 2ull * Mn * 16 * 4 + 2ull * Mn * 4;
  const int nch = (ws_size >= FULL_NEED) ? 1 : 2;
  const int nb = Bn / nch;
  const size_t rowsC = (size_t)nb * Tn;       // rows per pass
  const size_t sA = rowsC * Cn * 2;           // fp16 plane bytes

  char* p = (char*)d_ws;
  u16* x_h = (u16*)p; p += sA;
  u16* xLT = (u16*)p; p += sA;                // x_l, later reused as xhT
  u16* xh  = (u16*)p; p += sA;
  u16* Pp  = (u16*)p; p += (size_t)nb * NTRI * 16384 * 2;
  u16* W_h = (u16*)p; p += (size_t)Cn * Cn * 2;
  float* mt = (float*)p; p += rowsC * 16 * 4;
  float* lt = (float*)p; p += rowsC * 16 * 4;
  float* Mr = (float*)p; p += rowsC * 4;
  float* Li = (float*)p; p += rowsC * 4;

  dim3 blk(256);
  ksplitW<<<dim3(Cn * Cn / 2048), blk, 0, stream>>>(W, W_h);
  for (int c = 0; c < nch; ++c) {
    const float* xc = x + (size_t)c * rowsC * Cn;
    float* oc = out + (size_t)c * rowsC * Cn;
    ksplitX<<<dim3((u32)(rowsC * Cn / 2048)), blk, 0, stream>>>(xc, x_h, xLT);
    k1_xh<<<dim3((u32)(rowsC / 128), Cn / 128), blk, 0, stream>>>(x_h, W_h, xh);
    k2_scores<<<dim3(NLIN2, nb), dim3(512), 0, stream>>>(x_h, xLT, xh, Pp, mt, lt);
    k3_stats<<<dim3((u32)(rowsC / 256)), blk, 0, stream>>>(mt, lt, Mr, Li);
    ktr<<<dim3(Tn / 128, Cn / 128, nb), blk, 0, stream>>>(xh, xLT);
    k4_out<<<dim3(16, Cn / 128, nb), blk, 0, stream>>>(Pp, xLT, mt, Mr, Li, oc);
  }
}

// Round 3
// 411.085 us; speedup vs baseline: 1.0589x; 1.0589x over previous
//
#include <hip/hip_runtime.h>
#include <stdint.h>

// Problem constants
#define Bn 8
#define Tn 2048
#define Cn 1024
#define Mn (Bn * Tn)
#define NTRI 136   // causal 128x128 tiles per batch: 16*17/2
#define NLIN2 72   // k2 tiles per batch: BM=128,BN=256 -> sum ceil((qt+1)/2)

typedef __attribute__((ext_vector_type(4))) float f32x4;
typedef _Float16 f16;
typedef __attribute__((ext_vector_type(8))) _Float16 f16x8;
typedef uint16_t u16;
typedef uint32_t u32;

static __device__ __forceinline__ u16 f2h(float f) {
  union { f16 h; u16 u; } c; c.h = (f16)f; return c.u;
}
static __device__ __forceinline__ f32x4 mfmaH(f16x8 a, f16x8 b, f32x4 c) {
  return __builtin_amdgcn_mfma_f32_16x16x32_f16(a, b, c, 0, 0, 0);
}
// async global->LDS, 16B/lane; LDS dest = wave-uniform base + lane*16.
static __device__ __forceinline__ void gld16(const void* g, void* l) {
  __builtin_amdgcn_global_load_lds(
      (const __attribute__((address_space(1))) u32*)g,
      (__attribute__((address_space(3))) u32*)l, 16, 0, 0);
}

// ---------------------------------------------------------------------------
// ksplitW: W fp32 -> fp16 hi only.
// ---------------------------------------------------------------------------
__global__ __launch_bounds__(256) void ksplitW(const float* __restrict__ s,
                                               u16* __restrict__ hi) {
  size_t i = ((size_t)blockIdx.x * 256 + threadIdx.x) * 8;
  float4 a = *(const float4*)(s + i), b = *(const float4*)(s + i + 4);
  float f[8] = {a.x, a.y, a.z, a.w, b.x, b.y, b.z, b.w};
  union { u16 u[8]; uint4 v; } H;
#pragma unroll
  for (int j = 0; j < 8; ++j) H.u[j] = f2h(f[j]);
  *(uint4*)(hi + i) = H.v;
}

// ---------------------------------------------------------------------------
// ksplitX: x fp32 -> fp16 hi + fp16 lo residual (~22-bit effective).
// ---------------------------------------------------------------------------
__global__ __launch_bounds__(256) void ksplitX(const float* __restrict__ s,
                                               u16* __restrict__ hi,
                                               u16* __restrict__ lo) {
  size_t i = ((size_t)blockIdx.x * 256 + threadIdx.x) * 8;
  float4 a = *(const float4*)(s + i), b = *(const float4*)(s + i + 4);
  float f[8] = {a.x, a.y, a.z, a.w, b.x, b.y, b.z, b.w};
  union { u16 u[8]; uint4 v; } H, L;
#pragma unroll
  for (int j = 0; j < 8; ++j) {
    f16 h = (f16)f[j];
    union { f16 h; u16 u; } ch; ch.h = h;
    H.u[j] = ch.u;
    L.u[j] = f2h(f[j] - (float)h);
  }
  *(uint4*)(hi + i) = H.v;
  *(uint4*)(lo + i) = L.v;
}

// ---------------------------------------------------------------------------
// K1: xh = x_h @ W_h^T  (1 fp16 MFMA term). 128x128 tile, BK=64 as two
// [128][32] half-buffers (bank-identical to the proven BK=32 layout).
// ---------------------------------------------------------------------------
__global__ __launch_bounds__(256) void k1_xh(const u16* __restrict__ x_h,
                                             const u16* __restrict__ W_h,
                                             u16* __restrict__ xh) {
  __shared__ __align__(16) u16 Ah[8192], Bh[8192];
  const int tid = threadIdx.x;
  const int m0 = blockIdx.x * 128, n0 = blockIdx.y * 128;
  const int wave = tid >> 6, lane = tid & 63;
  const int wrow = (wave >> 1) * 64, wcol = (wave & 1) * 64;
  const int quad = lane >> 4, l16 = lane & 15;

  f32x4 acc[4][4] = {};

  for (int k0 = 0; k0 < Cn; k0 += 64) {
#pragma unroll
    for (int i = 0; i < 4; ++i) {
      int chunk = i * 256 + tid;
      int kk = chunk >> 9, row = (chunk >> 2) & 127, c8 = (chunk & 3) * 8;
      gld16(x_h + (size_t)(m0 + row) * Cn + k0 + kk * 32 + c8, Ah + chunk * 8);
      gld16(W_h + (size_t)(n0 + row) * Cn + k0 + kk * 32 + c8, Bh + chunk * 8);
    }
    __syncthreads();
#pragma unroll
    for (int kk = 0; kk < 2; ++kk) {
      f16x8 a[4], b[4];
#pragma unroll
      for (int i = 0; i < 4; ++i) {
        a[i] = *(const f16x8*)(Ah + kk * 4096 + (wrow + i * 16 + l16) * 32 + quad * 8);
        b[i] = *(const f16x8*)(Bh + kk * 4096 + (wcol + i * 16 + l16) * 32 + quad * 8);
      }
#pragma unroll
      for (int mi = 0; mi < 4; ++mi)
#pragma unroll
        for (int ni = 0; ni < 4; ++ni)
          acc[mi][ni] = mfmaH(a[mi], b[ni], acc[mi][ni]);
    }
    __syncthreads();
  }
#pragma unroll
  for (int mi = 0; mi < 4; ++mi)
#pragma unroll
    for (int ni = 0; ni < 4; ++ni)
#pragma unroll
      for (int r = 0; r < 4; ++r) {
        int row = wrow + mi * 16 + quad * 4 + r;
        int col = wcol + ni * 16 + l16;
        xh[(size_t)(m0 + row) * Cn + n0 + col] = f2h(acc[mi][ni][r]);
      }
}

// ---------------------------------------------------------------------------
// K2: S = (x_h + x_l) @ xh^T (2 terms); causal BM=128 x BN=256 tiles.
// LATENCY-BOUND fix: 2-phase double-buffered staging. Each iteration issues
// next-step gld16 prefetch FIRST, then ds_read+MFMA on the current buffer,
// then ONE __syncthreads (its vmcnt(0) drain lands after the MFMA cluster,
// hiding load latency under compute). 1 barrier/step instead of 2.
// LDS 64KB (2 blocks/CU); hiding shifts from TLP to ILP.
// ---------------------------------------------------------------------------
__global__ __launch_bounds__(512) void k2_scores(const u16* __restrict__ x_h,
                                                 const u16* __restrict__ x_l,
                                                 const u16* __restrict__ xh,
                                                 u16* __restrict__ P,
                                                 float* __restrict__ mt,
                                                 float* __restrict__ lt) {
  __shared__ __align__(16) union {
    struct { u16 Ah[2][4096], Al[2][4096], Bh[2][8192]; } s;  // dbuf planes
    struct { float Mrow[4][128]; float Lrow[4][128]; } e;
  } u;
  const int tid = threadIdx.x;
  const int bL = blockIdx.y;
  const int lin = blockIdx.x;
  int qt = 0, cum = 0;
  while (cum + ((qt >> 1) + 1) <= lin) { cum += (qt >> 1) + 1; qt++; }
  const int bcol = lin - cum;
  const int t0 = qt * 128, s0 = bcol * 256;
  const int wave = tid >> 6, lane = tid & 63;
  const int wc = wave & 3;
  const int wrow = (wave >> 2) * 64, wcol = wc * 64;
  const int quad = lane >> 4, l16 = lane & 15;

  f32x4 acc[4][4] = {};
  const size_t abase = ((size_t)bL * Tn + t0) * Cn;
  const size_t bbase = ((size_t)bL * Tn + s0) * Cn;
  const int arow = tid >> 2, ac8 = (tid & 3) * 8;

  auto stage = [&](int buf, int k0) {
    size_t aoff = abase + (size_t)arow * Cn + k0 + ac8;
    gld16(x_h + aoff, u.s.Ah[buf] + tid * 8);
    gld16(x_l + aoff, u.s.Al[buf] + tid * 8);
#pragma unroll
    for (int i = 0; i < 2; ++i) {
      int ch = i * 512 + tid;
      int row = ch >> 2, c8 = (ch & 3) * 8;
      gld16(xh + bbase + (size_t)row * Cn + k0 + c8, u.s.Bh[buf] + ch * 8);
    }
  };

  stage(0, 0);
  __syncthreads();
  int cur = 0;
  for (int k0 = 0; k0 < Cn; k0 += 32) {
    if (k0 + 32 < Cn) stage(cur ^ 1, k0 + 32);   // prefetch next K-step
    f16x8 b[4];
#pragma unroll
    for (int ni = 0; ni < 4; ++ni)
      b[ni] = *(const f16x8*)(u.s.Bh[cur] + (wcol + ni * 16 + l16) * 32 + quad * 8);
#pragma unroll
    for (int mi = 0; mi < 4; ++mi) {
      f16x8 ah = *(const f16x8*)(u.s.Ah[cur] + (wrow + mi * 16 + l16) * 32 + quad * 8);
      f16x8 al = *(const f16x8*)(u.s.Al[cur] + (wrow + mi * 16 + l16) * 32 + quad * 8);
#pragma unroll
      for (int ni = 0; ni < 4; ++ni) {
        acc[mi][ni] = mfmaH(ah, b[ni], acc[mi][ni]);
        acc[mi][ni] = mfmaH(al, b[ni], acc[mi][ni]);
      }
    }
    __syncthreads();   // drains this iter's prefetch (after MFMA) + publishes
    cur ^= 1;
  }

  // ---- epilogue: mask, per-row max (per 128-half), exp, stats, packed-P ----
  float rm[4][4];
#pragma unroll
  for (int mi = 0; mi < 4; ++mi)
#pragma unroll
    for (int r = 0; r < 4; ++r) {
      int row = wrow + mi * 16 + quad * 4 + r;
      float m = -1e30f;
#pragma unroll
      for (int ni = 0; ni < 4; ++ni) {
        int scol = s0 + wcol + ni * 16 + l16;
        if (scol >= t0 + row) acc[mi][ni][r] = -1e30f;
        m = fmaxf(m, acc[mi][ni][r]);
      }
      m = fmaxf(m, __shfl_xor(m, 1));
      m = fmaxf(m, __shfl_xor(m, 2));
      m = fmaxf(m, __shfl_xor(m, 4));
      m = fmaxf(m, __shfl_xor(m, 8));
      rm[mi][r] = m;
    }
  if (l16 == 0) {
#pragma unroll
    for (int mi = 0; mi < 4; ++mi)
#pragma unroll
      for (int r = 0; r < 4; ++r)
        u.e.Mrow[wc][wrow + mi * 16 + quad * 4 + r] = rm[mi][r];
  }
  __syncthreads();
  const int h2 = (wc >> 1) * 2;  // partner pair covering this 128-half
  float rs[4][4];
#pragma unroll
  for (int mi = 0; mi < 4; ++mi)
#pragma unroll
    for (int r = 0; r < 4; ++r) {
      int row = wrow + mi * 16 + quad * 4 + r;
      float m2 = fmaxf(u.e.Mrow[h2][row], u.e.Mrow[h2 + 1][row]);
      float s = 0.f;
#pragma unroll
      for (int ni = 0; ni < 4; ++ni) {
        int scol = s0 + wcol + ni * 16 + l16;
        float p = (scol < t0 + row) ? __expf(acc[mi][ni][r] - m2) : 0.0f;
        acc[mi][ni][r] = p;
        s += p;
      }
      s += __shfl_xor(s, 1);
      s += __shfl_xor(s, 2);
      s += __shfl_xor(s, 4);
      s += __shfl_xor(s, 8);
      rs[mi][r] = s;
      rm[mi][r] = m2;
    }
  if (l16 == 0) {
#pragma unroll
    for (int mi = 0; mi < 4; ++mi)
#pragma unroll
      for (int r = 0; r < 4; ++r)
        u.e.Lrow[wc][wrow + mi * 16 + quad * 4 + r] = rs[mi][r];
  }
  __syncthreads();
  const int st128 = bcol * 2 + (wc >> 1);
  if (st128 <= qt) {  // even-qt diagonal rows have a dead right half-tile
    if ((wc & 1) == 0 && l16 == 0) {
#pragma unroll
      for (int mi = 0; mi < 4; ++mi)
#pragma unroll
        for (int r = 0; r < 4; ++r) {
          int row = wrow + mi * 16 + quad * 4 + r;
          size_t rI = (size_t)bL * Tn + t0 + row;
          mt[rI * 16 + st128] = rm[mi][r];
          lt[rI * 16 + st128] = u.e.Lrow[wc][row] + u.e.Lrow[wc + 1][row];
        }
    }
    const size_t pbase = (size_t)(bL * NTRI + qt * (qt + 1) / 2 + st128) * 16384;
#pragma unroll
    for (int mi = 0; mi < 4; ++mi)
#pragma unroll
      for (int ni = 0; ni < 4; ++ni)
#pragma unroll
        for (int r = 0; r < 4; ++r) {
          int row = wrow + mi * 16 + quad * 4 + r;
          int pcol = (wcol & 64) + ni * 16 + l16;
          P[pbase + row * 128 + pcol] = f2h(acc[mi][ni][r]);
        }
  }
}

// ---------------------------------------------------------------------------
// K3: per-row global max M and inverse denom Li. Row t=0 -> Li=0.
// ---------------------------------------------------------------------------
__global__ __launch_bounds__(256) void k3_stats(const float* __restrict__ mt,
                                                const float* __restrict__ lt,
                                                float* __restrict__ Mr,
                                                float* __restrict__ Li) {
  int r = blockIdx.x * 256 + threadIdx.x;
  int t = r & (Tn - 1);
  int nt = (t == 0) ? 0 : (((t - 1) >> 7) + 1);
  float M = -1e30f;
  for (int i = 0; i < nt; ++i) M = fmaxf(M, mt[(size_t)r * 16 + i]);
  float L = 0.f;
  for (int i = 0; i < nt; ++i) L += lt[(size_t)r * 16 + i] * __expf(mt[(size_t)r * 16 + i] - M);
  Mr[r] = M;
  Li[r] = (L > 0.f) ? 1.f / L : 0.f;
}

// ---------------------------------------------------------------------------
// ktr: xhT[b][c][s] = xh[b][s][c]  (fp16, 128x128 LDS tiles)
// ---------------------------------------------------------------------------
__global__ __launch_bounds__(256) void ktr(const u16* __restrict__ src,
                                           u16* __restrict__ dst) {
  __shared__ __align__(16) u16 S[128 * 136];
  const int t0 = blockIdx.x * 128, c0 = blockIdx.y * 128, b = blockIdx.z;
  const int tid = threadIdx.x;
#pragma unroll
  for (int i = 0; i < 8; ++i) {
    int chunk = tid + i * 256;
    int row = chunk >> 4, c8 = (chunk & 15) * 8;
    uint4 v = *(const uint4*)(src + ((size_t)b * Tn + t0 + row) * Cn + c0 + c8);
    *(uint4*)(S + row * 136 + c8) = v;
  }
  __syncthreads();
#pragma unroll
  for (int i = 0; i < 8; ++i) {
    int chunk = tid + i * 256;
    int crow = chunk >> 4, t8 = (chunk & 15) * 8;
    union { u16 s[8]; uint4 v; } o;
#pragma unroll
    for (int j = 0; j < 8; ++j) o.s[j] = S[(t8 + j) * 136 + crow];
    *(uint4*)(dst + ((size_t)b * Cn + c0 + crow) * Tn + t0 + t8) = o.v;
  }
}

// ---------------------------------------------------------------------------
// K4: out = -( (P*alpha) @ xh ), alpha folded into the A fragment.
// A = packed P tiles; B = xhT (k=s contig). BK=64 (two [128][32] halves).
// ---------------------------------------------------------------------------
__global__ __launch_bounds__(256) void k4_out(const u16* __restrict__ P,
                                              const u16* __restrict__ xhT,
                                              const float* __restrict__ mt,
                                              const float* __restrict__ Mr,
                                              const float* __restrict__ Li,
                                              float* __restrict__ out) {
  __shared__ __align__(16) u16 Ap[8192], Bp[8192];
  const int tid = threadIdx.x;
  const int tt = 15 - blockIdx.x;  // heavy tiles first
  const int cn = blockIdx.y, bL = blockIdx.z;
  const int t0 = tt * 128, c0 = cn * 128;
  const int wave = tid >> 6, lane = tid & 63;
  const int wrow = (wave >> 1) * 64, wcol = (wave & 1) * 64;
  const int quad = lane >> 4, l16 = lane & 15;

  f32x4 acc[4][4] = {};
  size_t rI[4]; float MrL[4], LiL[4];
#pragma unroll
  for (int mi = 0; mi < 4; ++mi) {
    rI[mi] = (size_t)bL * Tn + t0 + wrow + mi * 16 + l16;
    MrL[mi] = Mr[rI[mi]];
    LiL[mi] = Li[rI[mi]];
  }
  const size_t bbase = ((size_t)bL * Cn + c0) * Tn;

  for (int st = 0; st <= tt; ++st) {
    f16 ah[4];
#pragma unroll
    for (int mi = 0; mi < 4; ++mi)
      ah[mi] = (f16)(__expf(mt[rI[mi] * 16 + st] - MrL[mi]) * LiL[mi]);
    const size_t pbase = (size_t)(bL * NTRI + tt * (tt + 1) / 2 + st) * 16384;
#pragma unroll 1
    for (int kl = 0; kl < 128; kl += 64) {
#pragma unroll
      for (int i = 0; i < 4; ++i) {
        int chunk = i * 256 + tid;
        int kk = chunk >> 9, row = (chunk >> 2) & 127, c8 = (chunk & 3) * 8;
        gld16(P + pbase + (size_t)row * 128 + kl + kk * 32 + c8, Ap + chunk * 8);
        gld16(xhT + bbase + (size_t)row * Tn + st * 128 + kl + kk * 32 + c8, Bp + chunk * 8);
      }
      __syncthreads();
#pragma unroll
      for (int kk = 0; kk < 2; ++kk) {
        f16x8 a[4], b[4];
#pragma unroll
        for (int i = 0; i < 4; ++i) {
          a[i] = *(const f16x8*)(Ap + kk * 4096 + (wrow + i * 16 + l16) * 32 + quad * 8);
          f16x8 sv;
#pragma unroll
          for (int j = 0; j < 8; ++j) sv[j] = ah[i];
          a[i] = a[i] * sv;
          b[i] = *(const f16x8*)(Bp + kk * 4096 + (wcol + i * 16 + l16) * 32 + quad * 8);
        }
#pragma unroll
        for (int mi = 0; mi < 4; ++mi)
#pragma unroll
          for (int ni = 0; ni < 4; ++ni)
            acc[mi][ni] = mfmaH(a[mi], b[ni], acc[mi][ni]);
      }
      __syncthreads();
    }
  }
#pragma unroll
  for (int mi = 0; mi < 4; ++mi)
#pragma unroll
    for (int ni = 0; ni < 4; ++ni)
#pragma unroll
      for (int r = 0; r < 4; ++r) {
        int row = wrow + mi * 16 + quad * 4 + r;
        int col = wcol + ni * 16 + l16;
        out[((size_t)bL * Tn + t0 + row) * Cn + c0 + col] = -acc[mi][ni][r];
      }
}

// ---------------------------------------------------------------------------
extern "C" void kernel_launch(void* const* d_in, const int* in_sizes, int n_in,
                              void* d_out, int out_size, void* d_ws, size_t ws_size,
                              hipStream_t stream) {
  (void)in_sizes; (void)n_in; (void)out_size;
  const float* x = (const float*)d_in[0];
  const float* W = (const float*)d_in[1];
  float* out = (float*)d_out;

  // full-batch path needs ~140.6 MB; else fall back to 2 chunks (~71 MB)
  const size_t FULL_NEED = 3ull * Mn * Cn * 2 + (size_t)Bn * NTRI * 16384 * 2 +
                           (size_t)Cn * Cn * 2 + 2ull * Mn * 16 * 4 + 2ull * Mn * 4;
  const int nch = (ws_size >= FULL_NEED) ? 1 : 2;
  const int nb = Bn / nch;
  const size_t rowsC = (size_t)nb * Tn;       // rows per pass
  const size_t sA = rowsC * Cn * 2;           // fp16 plane bytes

  char* p = (char*)d_ws;
  u16* x_h = (u16*)p; p += sA;
  u16* xLT = (u16*)p; p += sA;                // x_l, later reused as xhT
  u16* xh  = (u16*)p; p += sA;
  u16* Pp  = (u16*)p; p += (size_t)nb * NTRI * 16384 * 2;
  u16* W_h = (u16*)p; p += (size_t)Cn * Cn * 2;
  float* mt = (float*)p; p += rowsC * 16 * 4;
  float* lt = (float*)p; p += rowsC * 16 * 4;
  float* Mr = (float*)p; p += rowsC * 4;
  float* Li = (float*)p; p += rowsC * 4;

  dim3 blk(256);
  ksplitW<<<dim3(Cn * Cn / 2048), blk, 0, stream>>>(W, W_h);
  for (int c = 0; c < nch; ++c) {
    const float* xc = x + (size_t)c * rowsC * Cn;
    float* oc = out + (size_t)c * rowsC * Cn;
    ksplitX<<<dim3((u32)(rowsC * Cn / 2048)), blk, 0, stream>>>(xc, x_h, xLT);
    k1_xh<<<dim3((u32)(rowsC / 128), Cn / 128), blk, 0, stream>>>(x_h, W_h, xh);
    k2_scores<<<dim3(NLIN2, nb), dim3(512), 0, stream>>>(x_h, xLT, xh, Pp, mt, lt);
    k3_stats<<<dim3((u32)(rowsC / 256)), blk, 0, stream>>>(mt, lt, Mr, Li);
    ktr<<<dim3(Tn / 128, Cn / 128, nb), blk, 0, stream>>>(xh, xLT);
    k4_out<<<dim3(16, Cn / 128, nb), blk, 0, stream>>>(Pp, xLT, mt, Mr, Li, oc);
  }
}